// Round 8
// baseline (261.682 us; speedup 1.0000x reference)
//
#include <hip/hip_runtime.h>

typedef unsigned short u16;
typedef short bf16x8 __attribute__((ext_vector_type(8)));
typedef float f32x4 __attribute__((ext_vector_type(4)));

#define CM 256

__device__ inline u16 f2bf(float f) {
    union { float f; unsigned u; } v; v.f = f;
    unsigned r = v.u + 0x7fffu + ((v.u >> 16) & 1u);
    return (u16)(r >> 16);
}

// ---------------------------------------------------------------------------
// k'' bit-interleave for the stage2->stage3 contraction index (c,e):
//   k''[0,1]=c[0,1]  k''[2]=e[0]  k''[3]=c[2]  k''[4:6]=e[1:3]
//   k''[7]=c[3]      k''[8]=e[4]  k''[9]=c[4]
// Session constraints learned (rounds 1-7):
//  * v_cvt_pk_bf16_f32 inline asm NaN'd -> f2bf only.
//  * Old 4i x 8j kB: acc2=128 AGPR + 128 arch = full 256 budget AND
//    outer_s=64KB -> hard 2 waves/SIMD; all ILP tricks inside that cap
//    exhausted (rounds 3/4/5). Round-8: 4i x 4j tile (64 AGPR, 32KB outer,
//    34.8KB staging) + launch_bounds(256,3) -> 3 waves/SIMD.
//  * wf/frag arrays MUST be #pragma unroll'd (rule #20, round 6: scratch).
//  * Total dur is kB-insensitive beyond ~±8us noise; kB is the largest
//    measurable pole (87us, MfmaUtil 15%, Occ 21%).
// ---------------------------------------------------------------------------

// k1: block-role merged prep + LayerNorm/projection. (Round-7 verified.)
//  bid <  512 : kA role — LayerNorm + dual projection (one i, 64 s each)
//  bid < 1024 : Wo_t transpose role (write-coalesced 2B stores)
//  bid < 1280 : norm role — norm_ws[i][j] = 1 / (eps + sum_s mask_si mask_sj)
__global__ __launch_bounds__(256, 2) void k1(
    const float* __restrict__ m, const float* __restrict__ mask,
    const float* __restrict__ ln_g, const float* __restrict__ ln_b,
    const float* __restrict__ Wa, const float* __restrict__ ba,
    const float* __restrict__ Wb, const float* __restrict__ bb,
    const float* __restrict__ Wo,
    u16* __restrict__ Wo_t, float* __restrict__ norm_ws,
    u16* __restrict__ a_t, u16* __restrict__ b_t)
{
    __shared__ u16 mn_s[64 * 264];   // [local row r][k], stride 264 (pad 8)
    const int bid = blockIdx.x, t = threadIdx.x;

    if (bid >= 512) {
        if (bid < 1024) {
            // ---- Wo_t transpose role ----
            int o = (bid - 512) * 256 + t;      // OUTPUT index (coalesced write)
            int z = o >> 10, kpp = o & 1023;
            int c = (kpp & 3) | (((kpp >> 3) & 1) << 2) | (((kpp >> 7) & 1) << 3)
                  | (((kpp >> 9) & 1) << 4);
            int e = ((kpp >> 2) & 1) | (((kpp >> 4) & 7) << 1) | (((kpp >> 8) & 1) << 4);
            Wo_t[o] = f2bf(Wo[(c * 32 + e) * 128 + z]);
        } else {
            // ---- norm role (reciprocal) ----
            int i = bid - 1024, j = t;
            float acc = 1e-3f;
            for (int s = 0; s < 128; s++)
                acc += mask[s * 256 + i] * mask[s * 256 + j];
            norm_ws[i * 256 + j] = 1.0f / acc;
        }
        return;
    }

    // ---- kA role: LayerNorm + dual projection ----
    const int w = t >> 6, lane = t & 63, quad = lane >> 4, lr = lane & 15;
    const int i_idx = bid >> 1;              // MSA column i
    const int sh = bid & 1;                  // s half: local r -> s = sh*64 + r

    const int n = w * 16 + lr;               // C/D col (0..63)
    const float* Wsrc = (n < 32) ? (Wa + n) : (Wb + (n - 32));
    bf16x8 wf[8];
#pragma unroll
    for (int ks = 0; ks < 8; ks++)
#pragma unroll
        for (int e = 0; e < 8; e++)
            wf[ks][e] = (short)f2bf(Wsrc[(ks * 32 + quad * 8 + e) * 32]);

    const float4 g4  = ((const float4*)ln_g)[lane];
    const float4 be4 = ((const float4*)ln_b)[lane];

#pragma unroll
    for (int rr = 0; rr < 16; rr++) {
        int r = w * 16 + rr;
        int grow = (sh * 64 + r) * 256 + i_idx;      // flat (s,i) row index
        float4 x = ((const float4*)m)[grow * 64 + lane];
        float s1 = x.x + x.y + x.z + x.w;
        float s2 = x.x * x.x + x.y * x.y + x.z * x.z + x.w * x.w;
        for (int off = 32; off; off >>= 1) {
            s1 += __shfl_xor(s1, off);
            s2 += __shfl_xor(s2, off);
        }
        float mu = s1 * (1.f / CM);
        float rstd = rsqrtf(s2 * (1.f / CM) - mu * mu + 1e-5f);
        ushort4 o;
        o.x = f2bf((x.x - mu) * rstd * g4.x + be4.x);
        o.y = f2bf((x.y - mu) * rstd * g4.y + be4.y);
        o.z = f2bf((x.z - mu) * rstd * g4.z + be4.z);
        o.w = f2bf((x.w - mu) * rstd * g4.w + be4.w);
        *(ushort4*)(&mn_s[r * 264 + lane * 4]) = o;
    }
    __syncthreads();

    f32x4 acc[4] = {};
#pragma unroll
    for (int ks = 0; ks < 8; ks++)
#pragma unroll
        for (int mt = 0; mt < 4; mt++) {
            bf16x8 af = *(const bf16x8*)(&mn_s[(mt * 16 + lr) * 264 + ks * 32 + quad * 8]);
            acc[mt] = __builtin_amdgcn_mfma_f32_16x16x32_bf16(af, wf[ks], acc[mt], 0, 0, 0);
        }

    const int cc = n & 31;
    const bool isB = n >= 32;
    const float bv = isB ? bb[cc] : ba[cc];
    u16* dst = isB ? b_t : a_t;
#pragma unroll
    for (int mt = 0; mt < 4; mt++) {
        int rbase = mt * 16 + quad * 4;          // C/D row base; reg contiguous
        int sbase = sh * 64 + rbase;
        ushort4 o;
        float v0 = (acc[mt][0] + bv) * mask[(sbase + 0) * 256 + i_idx];
        float v1 = (acc[mt][1] + bv) * mask[(sbase + 1) * 256 + i_idx];
        float v2 = (acc[mt][2] + bv) * mask[(sbase + 2) * 256 + i_idx];
        float v3 = (acc[mt][3] + bv) * mask[(sbase + 3) * 256 + i_idx];
        o.x = f2bf(v0); o.y = f2bf(v1); o.z = f2bf(v2); o.w = f2bf(v3);
        *(ushort4*)(dst + (i_idx * 32 + cc) * 128 + sbase) = o;
    }
}

// ---------------------------------------------------------------------------
// kB: fused outer-product + Wo projection. Round-8: tile 4i x 4j (16 pairs),
// grid (64,64), 256 thr, launch_bounds(256,3) -> target 3 waves/SIMD.
//  * acc2[4][4] = 64 AGPR; outer_s [16][1024] = 32 KB; staging 2x[128][68]
//    = 34.8 KB (max LDS 34.8 KB < 53.3 KB 3-block cap).
//  * stride-68 staging: frag-read bank (2*row+4*quad)%32 -> 4-way (was
//    8-way at stride-72).
//  * Stage-3: M=16 (one a3 row set), N=32/wave, depth-2 Wo_t + depth-1 a3
//    prefetch (round-5 verified pattern).
// ---------------------------------------------------------------------------
__global__ __launch_bounds__(256, 3) void kB(
    const u16* __restrict__ a_t, const u16* __restrict__ b_t,
    const u16* __restrict__ Wo_t, const float* __restrict__ bo,
    const float* __restrict__ norm_ws, float* __restrict__ out)
{
    __shared__ __align__(16) u16 smem[17408];     // 34,816 B
    u16* a_s = smem;                  // [128][68]
    u16* b_s = smem + 128 * 68;       // [128][68]
    u16* outer_s = smem;              // overlay after stage 2: [16][1024]

    const int t = threadIdx.x;
    const int w = t >> 6, lane = t & 63, quad = lane >> 4, lr = lane & 15;
    const int wm = w >> 1, wn = w & 1;
    const u16* ag = a_t + blockIdx.x * (128 * 128);
    const u16* bg = b_t + blockIdx.y * (128 * 128);

    // ---- stage 2: two K=64 halves through LDS ----
    f32x4 acc2[4][4] = {};
    for (int kh = 0; kh < 2; kh++) {
#pragma unroll
        for (int q = 0; q < 4; q++) {
            int flat = q * 2048 + t * 8;          // a: 128 rows x 64 k
            int mm = flat >> 6, kk = flat & 63;
            *(uint4*)(&a_s[mm * 68 + kk]) = *(const uint4*)(ag + mm * 128 + kh * 64 + kk);
        }
#pragma unroll
        for (int q = 0; q < 4; q++) {
            int flat = q * 2048 + t * 8;          // b: 128 rows x 64 k
            int mm = flat >> 6, kk = flat & 63;
            *(uint4*)(&b_s[mm * 68 + kk]) = *(const uint4*)(bg + mm * 128 + kh * 64 + kk);
        }
        __syncthreads();
#pragma unroll
        for (int ks = 0; ks < 2; ks++) {
            int k0 = ks * 32 + quad * 8;
            bf16x8 af[4], bfr[4];
#pragma unroll
            for (int tm = 0; tm < 4; tm++)
                af[tm] = *(const bf16x8*)(&a_s[(wm * 64 + tm * 16 + lr) * 68 + k0]);
#pragma unroll
            for (int tn = 0; tn < 4; tn++)
                bfr[tn] = *(const bf16x8*)(&b_s[(wn * 64 + tn * 16 + lr) * 68 + k0]);
#pragma unroll
            for (int tm = 0; tm < 4; tm++)
#pragma unroll
                for (int tn = 0; tn < 4; tn++)
                    acc2[tm][tn] = __builtin_amdgcn_mfma_f32_16x16x32_bf16(
                        af[tm], bfr[tn], acc2[tm][tn], 0, 0, 0);
        }
        __syncthreads();
    }

    // ---- epilogue stage 2: swizzled packed store to outer_s ----
    // value = outer[c][e]; c = (tm&1)*16 + quad*4 + reg, e = (tn&1)*16 + lr
    // p = i_l*4 + j_l, i_l = wm*2 + (tm>>1), j_l = wn*2 + (tn>>1)
#pragma unroll
    for (int tm = 0; tm < 4; tm++)
#pragma unroll
        for (int tn = 0; tn < 4; tn++) {
            int p  = (wm * 2 + (tm >> 1)) * 4 + wn * 2 + (tn >> 1);
            int cI = (quad & 1) | ((lr >> 1) << 1) | ((quad >> 1) << 4)
                   | ((tn & 1) << 5) | ((tm & 1) << 6);
            int pi = cI ^ (p & 7);
            ushort4 o;
            o.x = f2bf(acc2[tm][tn][0]);
            o.y = f2bf(acc2[tm][tn][1]);
            o.z = f2bf(acc2[tm][tn][2]);
            o.w = f2bf(acc2[tm][tn][3]);
            *(ushort4*)(&outer_s[p * 1024 + pi * 8 + 4 * (lr & 1)]) = o;
        }
    __syncthreads();

    // ---- stage 3: [16 p][1024 k''] @ Wo_t -> [16 p][128 z] ----
    // depth-2 Wo_t prefetch + depth-1 a3 LDS prefetch (round-5 pattern).
    const int n0w = w * 32;
    const u16* wp0 = Wo_t + (n0w + lr) * 1024;
    const u16* wp1 = Wo_t + (n0w + 16 + lr) * 1024;
    f32x4 acc3[2] = {};
    bf16x8 b3c[2], b3n[2];
    {
        int k0 = quad * 8;
        b3c[0] = *(const bf16x8*)(wp0 + k0);
        b3c[1] = *(const bf16x8*)(wp1 + k0);
        b3n[0] = *(const bf16x8*)(wp0 + 32 + k0);
        b3n[1] = *(const bf16x8*)(wp1 + 32 + k0);
    }
    bf16x8 a3c, a3n;
    {
        int pi = quad ^ (lr & 7);
        a3c = *(const bf16x8*)(&outer_s[lr * 1024 + pi * 8]);
    }
    for (int ks = 0; ks < 32; ks++) {
        if (ks < 31) {
            int pi = ((ks + 1) * 4 + quad) ^ (lr & 7);
            a3n = *(const bf16x8*)(&outer_s[lr * 1024 + pi * 8]);
        }
        bf16x8 pf0, pf1;
        if (ks < 30) {
            int k2 = (ks + 2) * 32 + quad * 8;
            pf0 = *(const bf16x8*)(wp0 + k2);
            pf1 = *(const bf16x8*)(wp1 + k2);
        }
        acc3[0] = __builtin_amdgcn_mfma_f32_16x16x32_bf16(a3c, b3c[0], acc3[0], 0, 0, 0);
        acc3[1] = __builtin_amdgcn_mfma_f32_16x16x32_bf16(a3c, b3c[1], acc3[1], 0, 0, 0);
        a3c = a3n;
        b3c[0] = b3n[0]; b3c[1] = b3n[1];
        b3n[0] = pf0;    b3n[1] = pf1;
    }

    // ---- epilogue: + bo, * (1/norm), store ----
    const int i0 = blockIdx.x * 4, j0 = blockIdx.y * 4;
#pragma unroll
    for (int reg = 0; reg < 4; reg++) {
        int p = quad * 4 + reg;                  // C/D row = pair index
        int ii = i0 + (p >> 2), jj = j0 + (p & 3);
        float rn = norm_ws[ii * 256 + jj];       // reciprocal (k1)
#pragma unroll
        for (int tt = 0; tt < 2; tt++) {
            int z = n0w + tt * 16 + lr;
            out[(ii * 256 + jj) * 128 + z] = (acc3[tt][reg] + bo[z]) * rn;
        }
    }
}

extern "C" void kernel_launch(void* const* d_in, const int* in_sizes, int n_in,
                              void* d_out, int out_size, void* d_ws, size_t ws_size,
                              hipStream_t stream)
{
    const float* m    = (const float*)d_in[0];
    const float* mask = (const float*)d_in[1];
    const float* ln_g = (const float*)d_in[2];
    const float* ln_b = (const float*)d_in[3];
    const float* Wa   = (const float*)d_in[4];
    const float* ba   = (const float*)d_in[5];
    const float* Wb   = (const float*)d_in[6];
    const float* bb   = (const float*)d_in[7];
    const float* Wo   = (const float*)d_in[8];
    const float* bo   = (const float*)d_in[9];
    float* out = (float*)d_out;

    char* ws = (char*)d_ws;
    u16*   a_t     = (u16*)ws;                        // 2 MB
    u16*   b_t     = (u16*)(ws + 0x200000);           // 2 MB
    u16*   Wo_t    = (u16*)(ws + 0x400000);           // 256 KB
    float* norm_ws = (float*)(ws + 0x448000);         // 256 KB

    hipLaunchKernelGGL(k1, dim3(1280), dim3(256), 0, stream,
                       m, mask, ln_g, ln_b, Wa, ba, Wb, bb, Wo,
                       Wo_t, norm_ws, a_t, b_t);
    hipLaunchKernelGGL(kB, dim3(64, 64), dim3(256), 0, stream,
                       a_t, b_t, Wo_t, bo, norm_ws, out);
}

// Round 9
// 180.729 us; speedup vs baseline: 1.4479x; 1.4479x over previous
//
#include <hip/hip_runtime.h>

typedef unsigned short u16;
typedef short bf16x8 __attribute__((ext_vector_type(8)));
typedef float f32x4 __attribute__((ext_vector_type(4)));

#define CM 256

__device__ inline u16 f2bf(float f) {
    union { float f; unsigned u; } v; v.f = f;
    unsigned r = v.u + 0x7fffu + ((v.u >> 16) & 1u);
    return (u16)(r >> 16);
}

// ---------------------------------------------------------------------------
// k'' bit-interleave for the stage2->stage3 contraction index (c,e):
//   k''[0,1]=c[0,1]  k''[2]=e[0]  k''[3]=c[2]  k''[4:6]=e[1:3]
//   k''[7]=c[3]      k''[8]=e[4]  k''[9]=c[4]
// Session constraints learned (rounds 1-8):
//  * v_cvt_pk_bf16_f32 inline asm NaN'd -> f2bf only.
//  * kB 4i x 8j + 2 blk/CU is the amortization optimum: 4i x 4j @ 3 blk/CU
//    DOUBLED kB (171 us, MfmaUtil 8%) — per-block overhead dominates, tile
//    must stay maximal (outer_s 64KB). Occupancy is a dead lever both ways.
//  * 128 arch VGPR cap: liveness across the stage-2 epilogue spills
//    (round 3); in-loop stage-3 additions (+16 VGPR) are spill-free
//    (round 5). Round-9 adds depth-3 Wo_t ring (+8 VGPR in-loop).
//  * Stage-2 2-phase batch staging beats K=32 double-buffer (round 4).
//  * wf/frag arrays MUST be #pragma unroll'd (rule #20, round 6).
// ---------------------------------------------------------------------------

// k1: block-role merged prep + LayerNorm/projection. (Round-7 verified.)
//  bid <  512 : kA role — LayerNorm + dual projection (one i, 64 s each)
//  bid < 1024 : Wo_t transpose role (write-coalesced 2B stores)
//  bid < 1280 : norm role — norm_ws[i][j] = 1 / (eps + sum_s mask_si mask_sj)
__global__ __launch_bounds__(256, 2) void k1(
    const float* __restrict__ m, const float* __restrict__ mask,
    const float* __restrict__ ln_g, const float* __restrict__ ln_b,
    const float* __restrict__ Wa, const float* __restrict__ ba,
    const float* __restrict__ Wb, const float* __restrict__ bb,
    const float* __restrict__ Wo,
    u16* __restrict__ Wo_t, float* __restrict__ norm_ws,
    u16* __restrict__ a_t, u16* __restrict__ b_t)
{
    __shared__ u16 mn_s[64 * 264];   // [local row r][k], stride 264 (pad 8)
    const int bid = blockIdx.x, t = threadIdx.x;

    if (bid >= 512) {
        if (bid < 1024) {
            // ---- Wo_t transpose role ----
            int o = (bid - 512) * 256 + t;      // OUTPUT index (coalesced write)
            int z = o >> 10, kpp = o & 1023;
            int c = (kpp & 3) | (((kpp >> 3) & 1) << 2) | (((kpp >> 7) & 1) << 3)
                  | (((kpp >> 9) & 1) << 4);
            int e = ((kpp >> 2) & 1) | (((kpp >> 4) & 7) << 1) | (((kpp >> 8) & 1) << 4);
            Wo_t[o] = f2bf(Wo[(c * 32 + e) * 128 + z]);
        } else {
            // ---- norm role (reciprocal) ----
            int i = bid - 1024, j = t;
            float acc = 1e-3f;
            for (int s = 0; s < 128; s++)
                acc += mask[s * 256 + i] * mask[s * 256 + j];
            norm_ws[i * 256 + j] = 1.0f / acc;
        }
        return;
    }

    // ---- kA role: LayerNorm + dual projection ----
    const int w = t >> 6, lane = t & 63, quad = lane >> 4, lr = lane & 15;
    const int i_idx = bid >> 1;              // MSA column i
    const int sh = bid & 1;                  // s half: local r -> s = sh*64 + r

    const int n = w * 16 + lr;               // C/D col (0..63)
    const float* Wsrc = (n < 32) ? (Wa + n) : (Wb + (n - 32));
    bf16x8 wf[8];
#pragma unroll
    for (int ks = 0; ks < 8; ks++)
#pragma unroll
        for (int e = 0; e < 8; e++)
            wf[ks][e] = (short)f2bf(Wsrc[(ks * 32 + quad * 8 + e) * 32]);

    const float4 g4  = ((const float4*)ln_g)[lane];
    const float4 be4 = ((const float4*)ln_b)[lane];

#pragma unroll
    for (int rr = 0; rr < 16; rr++) {
        int r = w * 16 + rr;
        int grow = (sh * 64 + r) * 256 + i_idx;      // flat (s,i) row index
        float4 x = ((const float4*)m)[grow * 64 + lane];
        float s1 = x.x + x.y + x.z + x.w;
        float s2 = x.x * x.x + x.y * x.y + x.z * x.z + x.w * x.w;
        for (int off = 32; off; off >>= 1) {
            s1 += __shfl_xor(s1, off);
            s2 += __shfl_xor(s2, off);
        }
        float mu = s1 * (1.f / CM);
        float rstd = rsqrtf(s2 * (1.f / CM) - mu * mu + 1e-5f);
        ushort4 o;
        o.x = f2bf((x.x - mu) * rstd * g4.x + be4.x);
        o.y = f2bf((x.y - mu) * rstd * g4.y + be4.y);
        o.z = f2bf((x.z - mu) * rstd * g4.z + be4.z);
        o.w = f2bf((x.w - mu) * rstd * g4.w + be4.w);
        *(ushort4*)(&mn_s[r * 264 + lane * 4]) = o;
    }
    __syncthreads();

    f32x4 acc[4] = {};
#pragma unroll
    for (int ks = 0; ks < 8; ks++)
#pragma unroll
        for (int mt = 0; mt < 4; mt++) {
            bf16x8 af = *(const bf16x8*)(&mn_s[(mt * 16 + lr) * 264 + ks * 32 + quad * 8]);
            acc[mt] = __builtin_amdgcn_mfma_f32_16x16x32_bf16(af, wf[ks], acc[mt], 0, 0, 0);
        }

    const int cc = n & 31;
    const bool isB = n >= 32;
    const float bv = isB ? bb[cc] : ba[cc];
    u16* dst = isB ? b_t : a_t;
#pragma unroll
    for (int mt = 0; mt < 4; mt++) {
        int rbase = mt * 16 + quad * 4;          // C/D row base; reg contiguous
        int sbase = sh * 64 + rbase;
        ushort4 o;
        float v0 = (acc[mt][0] + bv) * mask[(sbase + 0) * 256 + i_idx];
        float v1 = (acc[mt][1] + bv) * mask[(sbase + 1) * 256 + i_idx];
        float v2 = (acc[mt][2] + bv) * mask[(sbase + 2) * 256 + i_idx];
        float v3 = (acc[mt][3] + bv) * mask[(sbase + 3) * 256 + i_idx];
        o.x = f2bf(v0); o.y = f2bf(v1); o.z = f2bf(v2); o.w = f2bf(v3);
        *(ushort4*)(dst + (i_idx * 32 + cc) * 128 + sbase) = o;
    }
}

// ---------------------------------------------------------------------------
// kB: fused outer-product + Wo projection. Tile 4i x 8j (32 pairs), grid
// (64,32), 256 thr. Round-9 = round-7 verified base (87 us) + ONE change:
// stage-3 Wo_t prefetch depth 2 -> 3 (named-register ring, +8 VGPR in-loop;
// raises outstanding L2 loads 4 -> 6 per wave — stage-3 is outstanding-
// load-count limited: ~2 B/cy/CU delivered vs ~13 demanded at depth-2).
// LDS: 64 KB. 128 arch VGPR + 128 acc -> 2 blocks/CU.
// ---------------------------------------------------------------------------
__global__ __launch_bounds__(256, 2) void kB(
    const u16* __restrict__ a_t, const u16* __restrict__ b_t,
    const u16* __restrict__ Wo_t, const float* __restrict__ bo,
    const float* __restrict__ norm_ws, float* __restrict__ out)
{
    __shared__ __align__(16) u16 smem[32768];     // 65,536 B
    u16* a_s = smem;                  // [128][72]
    u16* b_s = smem + 128 * 72;       // [256][72]
    u16* outer_s = smem;              // overlay after stage 2: [32][1024]

    const int t = threadIdx.x;
    const int w = t >> 6, lane = t & 63, quad = lane >> 4, lr = lane & 15;
    const int wm = w >> 1, wn = w & 1;
    const u16* ag = a_t + blockIdx.x * (128 * 128);
    const u16* bg = b_t + blockIdx.y * (256 * 128);

    // ---- stage 2: two K=64 halves through LDS ----
    f32x4 acc2[4][8] = {};
    for (int kh = 0; kh < 2; kh++) {
        for (int q = 0; q < 4; q++) {
            int flat = q * 2048 + t * 8;          // a: 128 rows x 64 k
            int mm = flat >> 6, kk = flat & 63;
            *(uint4*)(&a_s[mm * 72 + kk]) = *(const uint4*)(ag + mm * 128 + kh * 64 + kk);
        }
        for (int q = 0; q < 8; q++) {
            int flat = q * 2048 + t * 8;          // b: 256 rows x 64 k
            int mm = flat >> 6, kk = flat & 63;
            *(uint4*)(&b_s[mm * 72 + kk]) = *(const uint4*)(bg + mm * 128 + kh * 64 + kk);
        }
        __syncthreads();
        for (int ks = 0; ks < 2; ks++) {
            int k0 = ks * 32 + quad * 8;
            bf16x8 af[4], bfr[8];
            for (int tm = 0; tm < 4; tm++)
                af[tm] = *(const bf16x8*)(&a_s[(wm * 64 + tm * 16 + lr) * 72 + k0]);
            for (int tn = 0; tn < 8; tn++)
                bfr[tn] = *(const bf16x8*)(&b_s[(wn * 128 + tn * 16 + lr) * 72 + k0]);
            for (int tm = 0; tm < 4; tm++)
                for (int tn = 0; tn < 8; tn++)
                    acc2[tm][tn] = __builtin_amdgcn_mfma_f32_16x16x32_bf16(
                        af[tm], bfr[tn], acc2[tm][tn], 0, 0, 0);
        }
        __syncthreads();
    }

    // ---- epilogue stage 2: swizzled packed store to outer_s ----
    // value = outer[c][e]; c = (tm&1)*16 + quad*4 + reg, e = (tn&1)*16 + lr
    // p = i_l*8 + j_l, i_l = wm*2 + (tm>>1), j_l = wn*4 + (tn>>1)
    for (int tm = 0; tm < 4; tm++)
        for (int tn = 0; tn < 8; tn++) {
            int p  = (wm * 2 + (tm >> 1)) * 8 + wn * 4 + (tn >> 1);
            int cI = (quad & 1) | ((lr >> 1) << 1) | ((quad >> 1) << 4)
                   | ((tn & 1) << 5) | ((tm & 1) << 6);
            int pi = cI ^ (p & 7);
            ushort4 o;
            o.x = f2bf(acc2[tm][tn][0]);
            o.y = f2bf(acc2[tm][tn][1]);
            o.z = f2bf(acc2[tm][tn][2]);
            o.w = f2bf(acc2[tm][tn][3]);
            *(ushort4*)(&outer_s[p * 1024 + pi * 8 + 4 * (lr & 1)]) = o;
        }
    __syncthreads();

    // ---- stage 3: [32 p][1024 k''] @ Wo_t -> [32 p][128 z] ----
    // depth-3 Wo_t prefetch (named ring b3c/b3n/b3p) + depth-1 a3 prefetch.
    const int n0w = w * 32;
    const u16* wp0 = Wo_t + (n0w + lr) * 1024;
    const u16* wp1 = Wo_t + (n0w + 16 + lr) * 1024;
    f32x4 acc3[2][2] = {};
    bf16x8 b3c[2], b3n[2], b3p[2];
    {
        int k0 = quad * 8;
        b3c[0] = *(const bf16x8*)(wp0 + k0);
        b3c[1] = *(const bf16x8*)(wp1 + k0);
        b3n[0] = *(const bf16x8*)(wp0 + 32 + k0);
        b3n[1] = *(const bf16x8*)(wp1 + 32 + k0);
        b3p[0] = *(const bf16x8*)(wp0 + 64 + k0);
        b3p[1] = *(const bf16x8*)(wp1 + 64 + k0);
    }
    bf16x8 a3c[2], a3n[2];
    {
        int pi = quad ^ (lr & 7);
        a3c[0] = *(const bf16x8*)(&outer_s[lr * 1024 + pi * 8]);
        a3c[1] = *(const bf16x8*)(&outer_s[(16 + lr) * 1024 + pi * 8]);
    }
    for (int ks = 0; ks < 32; ks++) {
        if (ks < 31) {
            int pi = ((ks + 1) * 4 + quad) ^ (lr & 7);
            a3n[0] = *(const bf16x8*)(&outer_s[lr * 1024 + pi * 8]);
            a3n[1] = *(const bf16x8*)(&outer_s[(16 + lr) * 1024 + pi * 8]);
        }
        bf16x8 pf0, pf1;
        if (ks < 29) {
            int k3 = (ks + 3) * 32 + quad * 8;
            pf0 = *(const bf16x8*)(wp0 + k3);
            pf1 = *(const bf16x8*)(wp1 + k3);
        }
        acc3[0][0] = __builtin_amdgcn_mfma_f32_16x16x32_bf16(a3c[0], b3c[0], acc3[0][0], 0, 0, 0);
        acc3[0][1] = __builtin_amdgcn_mfma_f32_16x16x32_bf16(a3c[0], b3c[1], acc3[0][1], 0, 0, 0);
        acc3[1][0] = __builtin_amdgcn_mfma_f32_16x16x32_bf16(a3c[1], b3c[0], acc3[1][0], 0, 0, 0);
        acc3[1][1] = __builtin_amdgcn_mfma_f32_16x16x32_bf16(a3c[1], b3c[1], acc3[1][1], 0, 0, 0);
        a3c[0] = a3n[0]; a3c[1] = a3n[1];
        b3c[0] = b3n[0]; b3c[1] = b3n[1];
        b3n[0] = b3p[0]; b3n[1] = b3p[1];
        b3p[0] = pf0;    b3p[1] = pf1;
    }

    // ---- epilogue: + bo, * (1/norm), store ----
    const int i0 = blockIdx.x * 4, j0 = blockIdx.y * 8;
    for (int mt = 0; mt < 2; mt++)
        for (int reg = 0; reg < 4; reg++) {
            int p = mt * 16 + quad * 4 + reg;
            int ii = i0 + (p >> 3), jj = j0 + (p & 7);
            float rn = norm_ws[ii * 256 + jj];   // reciprocal (k1)
            for (int tt = 0; tt < 2; tt++) {
                int z = n0w + tt * 16 + lr;
                out[(ii * 256 + jj) * 128 + z] = (acc3[mt][tt][reg] + bo[z]) * rn;
            }
        }
}

extern "C" void kernel_launch(void* const* d_in, const int* in_sizes, int n_in,
                              void* d_out, int out_size, void* d_ws, size_t ws_size,
                              hipStream_t stream)
{
    const float* m    = (const float*)d_in[0];
    const float* mask = (const float*)d_in[1];
    const float* ln_g = (const float*)d_in[2];
    const float* ln_b = (const float*)d_in[3];
    const float* Wa   = (const float*)d_in[4];
    const float* ba   = (const float*)d_in[5];
    const float* Wb   = (const float*)d_in[6];
    const float* bb   = (const float*)d_in[7];
    const float* Wo   = (const float*)d_in[8];
    const float* bo   = (const float*)d_in[9];
    float* out = (float*)d_out;

    char* ws = (char*)d_ws;
    u16*   a_t     = (u16*)ws;                        // 2 MB
    u16*   b_t     = (u16*)(ws + 0x200000);           // 2 MB
    u16*   Wo_t    = (u16*)(ws + 0x400000);           // 256 KB
    float* norm_ws = (float*)(ws + 0x448000);         // 256 KB

    hipLaunchKernelGGL(k1, dim3(1280), dim3(256), 0, stream,
                       m, mask, ln_g, ln_b, Wa, ba, Wb, bb, Wo,
                       Wo_t, norm_ws, a_t, b_t);
    hipLaunchKernelGGL(kB, dim3(64, 32), dim3(256), 0, stream,
                       a_t, b_t, Wo_t, bo, norm_ws, out);
}

// Round 10
// 179.466 us; speedup vs baseline: 1.4581x; 1.0070x over previous
//
#include <hip/hip_runtime.h>

typedef unsigned short u16;
typedef short bf16x8 __attribute__((ext_vector_type(8)));
typedef float f32x4 __attribute__((ext_vector_type(4)));

#define CM 256

__device__ inline u16 f2bf(float f) {
    union { float f; unsigned u; } v; v.f = f;
    unsigned r = v.u + 0x7fffu + ((v.u >> 16) & 1u);
    return (u16)(r >> 16);
}

// ---------------------------------------------------------------------------
// k'' bit-interleave for the stage2->stage3 contraction index (c,e):
//   k''[0,1]=c[0,1]  k''[2]=e[0]  k''[3]=c[2]  k''[4:6]=e[1:3]
//   k''[7]=c[3]      k''[8]=e[4]  k''[9]=c[4]
// Session constraints learned (rounds 1-9):
//  * v_cvt_pk_bf16_f32 inline asm NaN'd -> f2bf only.
//  * kB is structurally wedged at 87 us: 4i x 8j + 2 blk/CU is the
//    amortization optimum (4i x 4j @ 3 blk/CU doubled time, round 8);
//    stage-2 re-pipelining regressed (round 4); Wo_t prefetch depth 3 = null
//    (round 9); a3 depth-1 prefetch is the one stage-3 win (round 5).
//    128 arch VGPR cap: no liveness across the stage-2 epilogue (round 3).
//  * wf/frag arrays MUST be #pragma unroll'd (rule #20, round 6).
//  * Fixed non-kernel overhead ~59 us (round-6 decomposition); k1 ~35 us vs
//    ~7 us floor -> round-10 target: k1's 192-shfl/thread reduction + 2 blk/CU.
// ---------------------------------------------------------------------------

// k1: block-role merged prep + LayerNorm/projection.
//  bid <  512 : kA role — LayerNorm + dual projection (one i, 64 s each)
//  bid < 1024 : Wo_t transpose role (write-coalesced 2B stores)
//  bid < 1280 : norm role — norm_ws[i][j] = 1 / (eps + sum_s mask_si mask_sj)
// Round-10: (a) LN reduce restructured to 16-lane groups — 4 rows per step,
// in-lane 16-elem sum + 4-deep shfl tree: 32 shfl/thread vs 192; (b)
// launch_bounds(256,4): 4 blocks/CU (LDS 33.8KB allows 4; regs ~70).
__global__ __launch_bounds__(256, 4) void k1(
    const float* __restrict__ m, const float* __restrict__ mask,
    const float* __restrict__ ln_g, const float* __restrict__ ln_b,
    const float* __restrict__ Wa, const float* __restrict__ ba,
    const float* __restrict__ Wb, const float* __restrict__ bb,
    const float* __restrict__ Wo,
    u16* __restrict__ Wo_t, float* __restrict__ norm_ws,
    u16* __restrict__ a_t, u16* __restrict__ b_t)
{
    __shared__ u16 mn_s[64 * 264];   // [local row r][k], stride 264 (pad 8)
    const int bid = blockIdx.x, t = threadIdx.x;

    if (bid >= 512) {
        if (bid < 1024) {
            // ---- Wo_t transpose role ----
            int o = (bid - 512) * 256 + t;      // OUTPUT index (coalesced write)
            int z = o >> 10, kpp = o & 1023;
            int c = (kpp & 3) | (((kpp >> 3) & 1) << 2) | (((kpp >> 7) & 1) << 3)
                  | (((kpp >> 9) & 1) << 4);
            int e = ((kpp >> 2) & 1) | (((kpp >> 4) & 7) << 1) | (((kpp >> 8) & 1) << 4);
            Wo_t[o] = f2bf(Wo[(c * 32 + e) * 128 + z]);
        } else {
            // ---- norm role (reciprocal) ----
            int i = bid - 1024, j = t;
            float acc = 1e-3f;
            for (int s = 0; s < 128; s++)
                acc += mask[s * 256 + i] * mask[s * 256 + j];
            norm_ws[i * 256 + j] = 1.0f / acc;
        }
        return;
    }

    // ---- kA role: LayerNorm + dual projection ----
    const int w = t >> 6, lane = t & 63, quad = lane >> 4, lr = lane & 15;
    const int g = quad, sl = lr;             // reduction naming: group-row, sub-lane
    const int i_idx = bid >> 1;              // MSA column i
    const int sh = bid & 1;                  // s half: local r -> s = sh*64 + r

    const int n = w * 16 + lr;               // C/D col (0..63)
    const float* Wsrc = (n < 32) ? (Wa + n) : (Wb + (n - 32));
    bf16x8 wf[8];
#pragma unroll
    for (int ks = 0; ks < 8; ks++)
#pragma unroll
        for (int e = 0; e < 8; e++)
            wf[ks][e] = (short)f2bf(Wsrc[(ks * 32 + quad * 8 + e) * 32]);

    // LN: 4 rows per step; lane sl owns float4-cols {q*16+sl}, q=0..3.
    // Row sum = in-lane 16-elem sum + 4-deep shfl tree over the 16-lane group.
#pragma unroll
    for (int rr = 0; rr < 4; rr++) {
        int r = w * 16 + rr * 4 + g;
        int grow = (sh * 64 + r) * 256 + i_idx;      // flat (s,i) row index
        const float4* mrow = (const float4*)m + grow * 64;
        float4 x0 = mrow[0 * 16 + sl];
        float4 x1 = mrow[1 * 16 + sl];
        float4 x2 = mrow[2 * 16 + sl];
        float4 x3 = mrow[3 * 16 + sl];
        float s1 = (x0.x + x0.y + x0.z + x0.w) + (x1.x + x1.y + x1.z + x1.w)
                 + (x2.x + x2.y + x2.z + x2.w) + (x3.x + x3.y + x3.z + x3.w);
        float s2 = (x0.x * x0.x + x0.y * x0.y + x0.z * x0.z + x0.w * x0.w)
                 + (x1.x * x1.x + x1.y * x1.y + x1.z * x1.z + x1.w * x1.w)
                 + (x2.x * x2.x + x2.y * x2.y + x2.z * x2.z + x2.w * x2.w)
                 + (x3.x * x3.x + x3.y * x3.y + x3.z * x3.z + x3.w * x3.w);
#pragma unroll
        for (int off = 8; off; off >>= 1) {
            s1 += __shfl_xor(s1, off);
            s2 += __shfl_xor(s2, off);
        }
        float mu = s1 * (1.f / CM);
        float rstd = rsqrtf(s2 * (1.f / CM) - mu * mu + 1e-5f);
        // normalize + write the 4 owned chunks (g/b reloaded per q: 1KB, L1-hot)
#pragma unroll
        for (int q = 0; q < 4; q++) {
            float4 x = (q == 0) ? x0 : (q == 1) ? x1 : (q == 2) ? x2 : x3;
            float4 g4  = ((const float4*)ln_g)[q * 16 + sl];
            float4 be4 = ((const float4*)ln_b)[q * 16 + sl];
            ushort4 o;
            o.x = f2bf((x.x - mu) * rstd * g4.x + be4.x);
            o.y = f2bf((x.y - mu) * rstd * g4.y + be4.y);
            o.z = f2bf((x.z - mu) * rstd * g4.z + be4.z);
            o.w = f2bf((x.w - mu) * rstd * g4.w + be4.w);
            *(ushort4*)(&mn_s[r * 264 + (q * 16 + sl) * 4]) = o;
        }
    }
    __syncthreads();

    f32x4 acc[4] = {};
#pragma unroll
    for (int ks = 0; ks < 8; ks++)
#pragma unroll
        for (int mt = 0; mt < 4; mt++) {
            bf16x8 af = *(const bf16x8*)(&mn_s[(mt * 16 + lr) * 264 + ks * 32 + quad * 8]);
            acc[mt] = __builtin_amdgcn_mfma_f32_16x16x32_bf16(af, wf[ks], acc[mt], 0, 0, 0);
        }

    const int cc = n & 31;
    const bool isB = n >= 32;
    const float bv = isB ? bb[cc] : ba[cc];
    u16* dst = isB ? b_t : a_t;
#pragma unroll
    for (int mt = 0; mt < 4; mt++) {
        int rbase = mt * 16 + quad * 4;          // C/D row base; reg contiguous
        int sbase = sh * 64 + rbase;
        ushort4 o;
        float v0 = (acc[mt][0] + bv) * mask[(sbase + 0) * 256 + i_idx];
        float v1 = (acc[mt][1] + bv) * mask[(sbase + 1) * 256 + i_idx];
        float v2 = (acc[mt][2] + bv) * mask[(sbase + 2) * 256 + i_idx];
        float v3 = (acc[mt][3] + bv) * mask[(sbase + 3) * 256 + i_idx];
        o.x = f2bf(v0); o.y = f2bf(v1); o.z = f2bf(v2); o.w = f2bf(v3);
        *(ushort4*)(dst + (i_idx * 32 + cc) * 128 + sbase) = o;
    }
}

// ---------------------------------------------------------------------------
// kB: fused outer-product + Wo projection. Tile 4i x 8j (32 pairs), grid
// (64,32), 256 thr. EXACT round-9 kernel (= round-7 best, 86.7-87.4 us):
// stage-2 2x K=64 batch stride-72; stage-3 depth-3 Wo_t ring + depth-1 a3
// prefetch. LDS 64 KB; 128 arch VGPR + 128 acc -> 2 blocks/CU. FROZEN.
// ---------------------------------------------------------------------------
__global__ __launch_bounds__(256, 2) void kB(
    const u16* __restrict__ a_t, const u16* __restrict__ b_t,
    const u16* __restrict__ Wo_t, const float* __restrict__ bo,
    const float* __restrict__ norm_ws, float* __restrict__ out)
{
    __shared__ __align__(16) u16 smem[32768];     // 65,536 B
    u16* a_s = smem;                  // [128][72]
    u16* b_s = smem + 128 * 72;       // [256][72]
    u16* outer_s = smem;              // overlay after stage 2: [32][1024]

    const int t = threadIdx.x;
    const int w = t >> 6, lane = t & 63, quad = lane >> 4, lr = lane & 15;
    const int wm = w >> 1, wn = w & 1;
    const u16* ag = a_t + blockIdx.x * (128 * 128);
    const u16* bg = b_t + blockIdx.y * (256 * 128);

    // ---- stage 2: two K=64 halves through LDS ----
    f32x4 acc2[4][8] = {};
    for (int kh = 0; kh < 2; kh++) {
        for (int q = 0; q < 4; q++) {
            int flat = q * 2048 + t * 8;          // a: 128 rows x 64 k
            int mm = flat >> 6, kk = flat & 63;
            *(uint4*)(&a_s[mm * 72 + kk]) = *(const uint4*)(ag + mm * 128 + kh * 64 + kk);
        }
        for (int q = 0; q < 8; q++) {
            int flat = q * 2048 + t * 8;          // b: 256 rows x 64 k
            int mm = flat >> 6, kk = flat & 63;
            *(uint4*)(&b_s[mm * 72 + kk]) = *(const uint4*)(bg + mm * 128 + kh * 64 + kk);
        }
        __syncthreads();
        for (int ks = 0; ks < 2; ks++) {
            int k0 = ks * 32 + quad * 8;
            bf16x8 af[4], bfr[8];
            for (int tm = 0; tm < 4; tm++)
                af[tm] = *(const bf16x8*)(&a_s[(wm * 64 + tm * 16 + lr) * 72 + k0]);
            for (int tn = 0; tn < 8; tn++)
                bfr[tn] = *(const bf16x8*)(&b_s[(wn * 128 + tn * 16 + lr) * 72 + k0]);
            for (int tm = 0; tm < 4; tm++)
                for (int tn = 0; tn < 8; tn++)
                    acc2[tm][tn] = __builtin_amdgcn_mfma_f32_16x16x32_bf16(
                        af[tm], bfr[tn], acc2[tm][tn], 0, 0, 0);
        }
        __syncthreads();
    }

    // ---- epilogue stage 2: swizzled packed store to outer_s ----
    // value = outer[c][e]; c = (tm&1)*16 + quad*4 + reg, e = (tn&1)*16 + lr
    // p = i_l*8 + j_l, i_l = wm*2 + (tm>>1), j_l = wn*4 + (tn>>1)
    for (int tm = 0; tm < 4; tm++)
        for (int tn = 0; tn < 8; tn++) {
            int p  = (wm * 2 + (tm >> 1)) * 8 + wn * 4 + (tn >> 1);
            int cI = (quad & 1) | ((lr >> 1) << 1) | ((quad >> 1) << 4)
                   | ((tn & 1) << 5) | ((tm & 1) << 6);
            int pi = cI ^ (p & 7);
            ushort4 o;
            o.x = f2bf(acc2[tm][tn][0]);
            o.y = f2bf(acc2[tm][tn][1]);
            o.z = f2bf(acc2[tm][tn][2]);
            o.w = f2bf(acc2[tm][tn][3]);
            *(ushort4*)(&outer_s[p * 1024 + pi * 8 + 4 * (lr & 1)]) = o;
        }
    __syncthreads();

    // ---- stage 3: [32 p][1024 k''] @ Wo_t -> [32 p][128 z] ----
    const int n0w = w * 32;
    const u16* wp0 = Wo_t + (n0w + lr) * 1024;
    const u16* wp1 = Wo_t + (n0w + 16 + lr) * 1024;
    f32x4 acc3[2][2] = {};
    bf16x8 b3c[2], b3n[2], b3p[2];
    {
        int k0 = quad * 8;
        b3c[0] = *(const bf16x8*)(wp0 + k0);
        b3c[1] = *(const bf16x8*)(wp1 + k0);
        b3n[0] = *(const bf16x8*)(wp0 + 32 + k0);
        b3n[1] = *(const bf16x8*)(wp1 + 32 + k0);
        b3p[0] = *(const bf16x8*)(wp0 + 64 + k0);
        b3p[1] = *(const bf16x8*)(wp1 + 64 + k0);
    }
    bf16x8 a3c[2], a3n[2];
    {
        int pi = quad ^ (lr & 7);
        a3c[0] = *(const bf16x8*)(&outer_s[lr * 1024 + pi * 8]);
        a3c[1] = *(const bf16x8*)(&outer_s[(16 + lr) * 1024 + pi * 8]);
    }
    for (int ks = 0; ks < 32; ks++) {
        if (ks < 31) {
            int pi = ((ks + 1) * 4 + quad) ^ (lr & 7);
            a3n[0] = *(const bf16x8*)(&outer_s[lr * 1024 + pi * 8]);
            a3n[1] = *(const bf16x8*)(&outer_s[(16 + lr) * 1024 + pi * 8]);
        }
        bf16x8 pf0, pf1;
        if (ks < 29) {
            int k3 = (ks + 3) * 32 + quad * 8;
            pf0 = *(const bf16x8*)(wp0 + k3);
            pf1 = *(const bf16x8*)(wp1 + k3);
        }
        acc3[0][0] = __builtin_amdgcn_mfma_f32_16x16x32_bf16(a3c[0], b3c[0], acc3[0][0], 0, 0, 0);
        acc3[0][1] = __builtin_amdgcn_mfma_f32_16x16x32_bf16(a3c[0], b3c[1], acc3[0][1], 0, 0, 0);
        acc3[1][0] = __builtin_amdgcn_mfma_f32_16x16x32_bf16(a3c[1], b3c[0], acc3[1][0], 0, 0, 0);
        acc3[1][1] = __builtin_amdgcn_mfma_f32_16x16x32_bf16(a3c[1], b3c[1], acc3[1][1], 0, 0, 0);
        a3c[0] = a3n[0]; a3c[1] = a3n[1];
        b3c[0] = b3n[0]; b3c[1] = b3n[1];
        b3n[0] = b3p[0]; b3n[1] = b3p[1];
        b3p[0] = pf0;    b3p[1] = pf1;
    }

    // ---- epilogue: + bo, * (1/norm), store ----
    const int i0 = blockIdx.x * 4, j0 = blockIdx.y * 8;
    for (int mt = 0; mt < 2; mt++)
        for (int reg = 0; reg < 4; reg++) {
            int p = mt * 16 + quad * 4 + reg;
            int ii = i0 + (p >> 3), jj = j0 + (p & 7);
            float rn = norm_ws[ii * 256 + jj];   // reciprocal (k1)
            for (int tt = 0; tt < 2; tt++) {
                int z = n0w + tt * 16 + lr;
                out[(ii * 256 + jj) * 128 + z] = (acc3[mt][tt][reg] + bo[z]) * rn;
            }
        }
}

extern "C" void kernel_launch(void* const* d_in, const int* in_sizes, int n_in,
                              void* d_out, int out_size, void* d_ws, size_t ws_size,
                              hipStream_t stream)
{
    const float* m    = (const float*)d_in[0];
    const float* mask = (const float*)d_in[1];
    const float* ln_g = (const float*)d_in[2];
    const float* ln_b = (const float*)d_in[3];
    const float* Wa   = (const float*)d_in[4];
    const float* ba   = (const float*)d_in[5];
    const float* Wb   = (const float*)d_in[6];
    const float* bb   = (const float*)d_in[7];
    const float* Wo   = (const float*)d_in[8];
    const float* bo   = (const float*)d_in[9];
    float* out = (float*)d_out;

    char* ws = (char*)d_ws;
    u16*   a_t     = (u16*)ws;                        // 2 MB
    u16*   b_t     = (u16*)(ws + 0x200000);           // 2 MB
    u16*   Wo_t    = (u16*)(ws + 0x400000);           // 256 KB
    float* norm_ws = (float*)(ws + 0x448000);         // 256 KB

    hipLaunchKernelGGL(k1, dim3(1280), dim3(256), 0, stream,
                       m, mask, ln_g, ln_b, Wa, ba, Wb, bb, Wo,
                       Wo_t, norm_ws, a_t, b_t);
    hipLaunchKernelGGL(kB, dim3(64, 32), dim3(256), 0, stream,
                       a_t, b_t, Wo_t, bo, norm_ws, out);
}